// Round 3
// baseline (915.751 us; speedup 1.0000x reference)
//
#include <hip/hip_runtime.h>

#define NN 8192

// K1: d[i] = 1/sqrt(rowsum(adj_row) + 1e-6), fp64 accumulation. One wave per row.
__global__ __launch_bounds__(256) void k1(const float* __restrict__ adj, double* __restrict__ d) {
    int row = blockIdx.x * 4 + (threadIdx.x >> 6);
    int l = threadIdx.x & 63;
    const float4* r = (const float4*)(adj + (size_t)row * NN) + l;
    double s = 0.0;
#pragma unroll 8
    for (int it = 0; it < 32; ++it) {
        float4 v = r[(size_t)it * 64];
        s += (double)v.x + (double)v.y + (double)v.z + (double)v.w;
    }
#pragma unroll
    for (int o = 32; o > 0; o >>= 1) s += __shfl_down(s, o);
    if (l == 0) d[row] = 1.0 / sqrt(s + 1e-6);
}

// K2: P[j][f] = f32( d_j * sum_c x[j][c]*W1[c][f] ), fp64 acc. 16 rows/block.
__global__ __launch_bounds__(256) void k2(const float* __restrict__ x, const float* __restrict__ W1,
                                          const double* __restrict__ d, float* __restrict__ P) {
    __shared__ float sw[128 * 64];
    __shared__ float sx[16 * 128];
    int tid = threadIdx.x;
    int jb = blockIdx.x * 16;
#pragma unroll
    for (int o = 0; o < 8; ++o)
        ((float4*)sw)[tid * 8 + o] = ((const float4*)W1)[tid * 8 + o];
#pragma unroll
    for (int o = 0; o < 2; ++o)
        ((float4*)sx)[tid * 2 + o] = ((const float4*)(x + (size_t)jb * 128))[tid * 2 + o];
    __syncthreads();
    int f = tid & 63, g = tid >> 6;
    double acc[4] = {0.0, 0.0, 0.0, 0.0};
    for (int c = 0; c < 128; ++c) {
        double w = (double)sw[c * 64 + f];
#pragma unroll
        for (int rr = 0; rr < 4; ++rr)
            acc[rr] += (double)sx[(g * 4 + rr) * 128 + c] * w;
    }
#pragma unroll
    for (int rr = 0; rr < 4; ++rr) {
        int j = jb + g * 4 + rr;
        P[(size_t)j * 64 + f] = (float)(acc[rr] * d[j]);
    }
}

// K3: agg1, fp64 acc, full K. Block = 16 rows x 64 f. Fused epilogue:
// h = relu(d_i*acc + b1[f]); q[i][c] = f32(d_i * wave_sum_f h*W2[f][c]). h never stored.
__global__ __launch_bounds__(256) void k3(const float* __restrict__ adj, const float* __restrict__ P,
                                          const double* __restrict__ d, const float* __restrict__ b1,
                                          const float* __restrict__ W2, float* __restrict__ q) {
    __shared__ float sp[128 * 64];  // P chunk [128 j][64 f]
    __shared__ float sa[16 * 128];  // adj tile [16 rows][128 j]
    int tid = threadIdx.x;
    int f = tid & 63, g = tid >> 6;
    int rb = blockIdx.x * 16;
    double acc[4] = {0.0, 0.0, 0.0, 0.0};
    for (int ch = 0; ch < 64; ++ch) {
        __syncthreads();
#pragma unroll
        for (int o = 0; o < 8; ++o)
            ((float4*)sp)[tid * 8 + o] = ((const float4*)(P + (size_t)ch * 128 * 64))[tid * 8 + o];
#pragma unroll
        for (int o = 0; o < 2; ++o) {
            int t = tid * 2 + o;           // 0..511
            int r = t >> 5, cv = t & 31;   // r<16, cv<32
            ((float4*)(sa + r * 128))[cv] = *(const float4*)(adj + (size_t)(rb + r) * NN + ch * 128 + cv * 4);
        }
        __syncthreads();
        const float* sar = sa + g * 4 * 128;
        for (int jj = 0; jj < 128; jj += 4) {
            float4 a0 = *(const float4*)(sar + jj);
            float4 a1 = *(const float4*)(sar + 128 + jj);
            float4 a2 = *(const float4*)(sar + 256 + jj);
            float4 a3 = *(const float4*)(sar + 384 + jj);
            double p0 = (double)sp[(jj + 0) * 64 + f];
            double p1 = (double)sp[(jj + 1) * 64 + f];
            double p2 = (double)sp[(jj + 2) * 64 + f];
            double p3 = (double)sp[(jj + 3) * 64 + f];
            acc[0] += (double)a0.x * p0 + (double)a0.y * p1 + (double)a0.z * p2 + (double)a0.w * p3;
            acc[1] += (double)a1.x * p0 + (double)a1.y * p1 + (double)a1.z * p2 + (double)a1.w * p3;
            acc[2] += (double)a2.x * p0 + (double)a2.y * p1 + (double)a2.z * p2 + (double)a2.w * p3;
            acc[3] += (double)a3.x * p0 + (double)a3.y * p1 + (double)a3.z * p2 + (double)a3.w * p3;
        }
    }
    double w0 = (double)W2[f * 2 + 0];
    double w1 = (double)W2[f * 2 + 1];
    double bb = (double)b1[f];
#pragma unroll
    for (int rr = 0; rr < 4; ++rr) {
        int row = rb + g * 4 + rr;
        double di = d[row];
        double h = di * acc[rr] + bb;
        h = h > 0.0 ? h : 0.0;
        double t0 = h * w0;
        double t1 = h * w1;
#pragma unroll
        for (int o = 32; o > 0; o >>= 1) {
            t0 += __shfl_down(t0, o);
            t1 += __shfl_down(t1, o);
        }
        if (f == 0) {
            q[(size_t)row * 2 + 0] = (float)(di * t0);
            q[(size_t)row * 2 + 1] = (float)(di * t1);
        }
    }
}

// K4: out[i][c] = f32( d_i * sum_j adj[i][j]*q[j][c] + b2[c] ), fp64 acc. One wave per row.
__global__ __launch_bounds__(256) void k4(const float* __restrict__ adj, const float* __restrict__ q,
                                          const double* __restrict__ d, const float* __restrict__ b2,
                                          float* __restrict__ out) {
    int row = blockIdx.x * 4 + (threadIdx.x >> 6);
    int l = threadIdx.x & 63;
    const float4* a = (const float4*)(adj + (size_t)row * NN) + l;
    const float4* qv = (const float4*)q;  // pairs: {q[j][0],q[j][1],q[j+1][0],q[j+1][1]}
    double acc0 = 0.0, acc1 = 0.0;
#pragma unroll 4
    for (int it = 0; it < 32; ++it) {
        float4 av = a[(size_t)it * 64];
        size_t jv = ((size_t)it * 64 + l) * 2;
        float4 qa = qv[jv];
        float4 qb = qv[jv + 1];
        acc0 += (double)av.x * qa.x + (double)av.y * qa.z + (double)av.z * qb.x + (double)av.w * qb.z;
        acc1 += (double)av.x * qa.y + (double)av.y * qa.w + (double)av.z * qb.y + (double)av.w * qb.w;
    }
#pragma unroll
    for (int o = 32; o > 0; o >>= 1) {
        acc0 += __shfl_down(acc0, o);
        acc1 += __shfl_down(acc1, o);
    }
    if (l == 0) {
        double di = d[row];
        out[(size_t)row * 2 + 0] = (float)(di * acc0 + (double)b2[0]);
        out[(size_t)row * 2 + 1] = (float)(di * acc1 + (double)b2[1]);
    }
}

extern "C" void kernel_launch(void* const* d_in, const int* in_sizes, int n_in,
                              void* d_out, int out_size, void* d_ws, size_t ws_size,
                              hipStream_t stream) {
    const float* x   = (const float*)d_in[0];
    const float* adj = (const float*)d_in[1];
    const float* W1  = (const float*)d_in[2];
    const float* b1  = (const float*)d_in[3];
    const float* W2  = (const float*)d_in[4];
    const float* b2  = (const float*)d_in[5];
    float* out = (float*)d_out;

    char* ws = (char*)d_ws;
    double* dvec = (double*)ws;                    // 8192 f64 = 64 KB
    float*  P    = (float*)(ws + 65536);           // 8192*64 f32 = 2 MB
    float*  q    = (float*)(ws + 65536 + 2097152); // 8192*2 f32 = 64 KB

    k1<<<2048, 256, 0, stream>>>(adj, dvec);
    k2<<<512, 256, 0, stream>>>(x, W1, dvec, P);
    k3<<<512, 256, 0, stream>>>(adj, P, dvec, b1, W2, q);
    k4<<<2048, 256, 0, stream>>>(adj, q, dvec, b2, out);
}

// Round 4
// 557.275 us; speedup vs baseline: 1.6433x; 1.6433x over previous
//
#include <hip/hip_runtime.h>

#define NN 8192
typedef unsigned short u16;
typedef __attribute__((ext_vector_type(8))) short short8;
typedef __attribute__((ext_vector_type(4))) float f32x4;

__device__ __forceinline__ u16 f2bf(float f) {  // round-to-nearest-even bf16
    unsigned u = __builtin_bit_cast(unsigned, f);
    return (u16)((u + 0x7FFFu + ((u >> 16) & 1u)) >> 16);
}
__device__ __forceinline__ float bf2f(u16 u) {
    unsigned v = ((unsigned)u) << 16;
    return __builtin_bit_cast(float, v);
}
__device__ __forceinline__ void split3(float v, u16& h, u16& m, u16& l) {
    h = f2bf(v);
    float r1 = v - bf2f(h);   // exact
    m = f2bf(r1);
    float r2 = r1 - bf2f(m);  // exact
    l = f2bf(r2);
}

// ---------------- K1: d[i] = 1/sqrt(rowsum + 1e-6), fp64. (proven in r3) ----------------
__global__ __launch_bounds__(256) void k1(const float* __restrict__ adj, double* __restrict__ d) {
    int row = blockIdx.x * 4 + (threadIdx.x >> 6);
    int l = threadIdx.x & 63;
    const float4* r = (const float4*)(adj + (size_t)row * NN) + l;
    double s = 0.0;
#pragma unroll 8
    for (int it = 0; it < 32; ++it) {
        float4 v = r[(size_t)it * 64];
        s += (double)v.x + (double)v.y + (double)v.z + (double)v.w;
    }
#pragma unroll
    for (int o = 32; o > 0; o >>= 1) s += __shfl_down(s, o);
    if (l == 0) d[row] = 1.0 / sqrt(s + 1e-6);
}

// ---------------- K2 (path A): Pt planes [64][NN] hi/mid/lo bf16, fp64 math ----------------
__global__ __launch_bounds__(256) void k2s(const float* __restrict__ x, const float* __restrict__ W1,
                                           const double* __restrict__ d, u16* __restrict__ Ph,
                                           u16* __restrict__ Pm, u16* __restrict__ Pl) {
    __shared__ float sw[128 * 64];
    __shared__ float sx[32 * 128];
    int tid = threadIdx.x;
    int jb = blockIdx.x * 32;
#pragma unroll
    for (int o = 0; o < 8; ++o)
        ((float4*)sw)[tid * 8 + o] = ((const float4*)W1)[tid * 8 + o];
#pragma unroll
    for (int o = 0; o < 4; ++o)
        ((float4*)sx)[tid * 4 + o] = ((const float4*)(x + (size_t)jb * 128))[tid * 4 + o];
    __syncthreads();
    int f = tid & 63, g = tid >> 6;
    double acc[8] = {};
    for (int c = 0; c < 128; ++c) {
        double w = (double)sw[c * 64 + f];
#pragma unroll
        for (int rr = 0; rr < 8; ++rr)
            acc[rr] += (double)sx[(g * 8 + rr) * 128 + c] * w;
    }
    short8 hv, mv, lv;
#pragma unroll
    for (int rr = 0; rr < 8; ++rr) {
        int j = jb + g * 8 + rr;
        float v = (float)(acc[rr] * d[j]);
        u16 hh, mm, ll;
        split3(v, hh, mm, ll);
        hv[rr] = (short)hh; mv[rr] = (short)mm; lv[rr] = (short)ll;
    }
    size_t off = (size_t)f * NN + jb + g * 8;
    *(short8*)(Ph + off) = hv;
    *(short8*)(Pm + off) = mv;
    *(short8*)(Pl + off) = lv;
}

// ---------------- K3 (path A): agg1 via 6-product split-bf16 MFMA, no LDS ----------------
__global__ __launch_bounds__(256) void k3s(const float* __restrict__ adj, const u16* __restrict__ Ph,
                                           const u16* __restrict__ Pm, const u16* __restrict__ Pl,
                                           float* __restrict__ part, int kspl, int klen) {
    int tid = threadIdx.x;
    int w = tid >> 6, l = tid & 63, q = l >> 4, n = l & 15;
    int outer = blockIdx.x / kspl, ks = blockIdx.x - outer * kspl;
    int rb = outer * 128 + w * 32;
    int k0 = ks * klen;
    f32x4 acc[2][4] = {};
    const float* a0 = adj + (size_t)(rb + n) * NN + k0 + q * 8;
    const float* a1 = a0 + (size_t)16 * NN;
    for (int kt = 0; kt < klen; kt += 32) {
        short8 ah[2], am[2], al[2];
#pragma unroll
        for (int rt = 0; rt < 2; ++rt) {
            const float* ap = (rt ? a1 : a0) + kt;
            float4 f0 = *(const float4*)ap;
            float4 f1 = *(const float4*)(ap + 4);
            float vv[8] = {f0.x, f0.y, f0.z, f0.w, f1.x, f1.y, f1.z, f1.w};
#pragma unroll
            for (int e = 0; e < 8; ++e) {
                u16 hh, mm, ll;
                split3(vv[e], hh, mm, ll);
                ah[rt][e] = (short)hh; am[rt][e] = (short)mm; al[rt][e] = (short)ll;
            }
        }
#pragma unroll
        for (int nt = 0; nt < 4; ++nt) {
            size_t boff = (size_t)(nt * 16 + n) * NN + k0 + kt + q * 8;
            short8 bh = *(const short8*)(Ph + boff);
            short8 bm = *(const short8*)(Pm + boff);
            short8 bl = *(const short8*)(Pl + boff);
#pragma unroll
            for (int rt = 0; rt < 2; ++rt) {
                f32x4 c = acc[rt][nt];
                c = __builtin_amdgcn_mfma_f32_16x16x32_bf16(ah[rt], bh, c, 0, 0, 0);
                c = __builtin_amdgcn_mfma_f32_16x16x32_bf16(ah[rt], bm, c, 0, 0, 0);
                c = __builtin_amdgcn_mfma_f32_16x16x32_bf16(am[rt], bh, c, 0, 0, 0);
                c = __builtin_amdgcn_mfma_f32_16x16x32_bf16(ah[rt], bl, c, 0, 0, 0);
                c = __builtin_amdgcn_mfma_f32_16x16x32_bf16(am[rt], bm, c, 0, 0, 0);
                c = __builtin_amdgcn_mfma_f32_16x16x32_bf16(al[rt], bh, c, 0, 0, 0);
                acc[rt][nt] = c;
            }
        }
    }
    float* pb = part + (size_t)ks * NN * 64;
#pragma unroll
    for (int rt = 0; rt < 2; ++rt)
#pragma unroll
        for (int nt = 0; nt < 4; ++nt)
#pragma unroll
            for (int r = 0; r < 4; ++r)
                pb[(size_t)(rb + rt * 16 + q * 4 + r) * 64 + nt * 16 + n] = acc[rt][nt][r];
}

// K3r: fp64 reduce of partials + fused epilogue: h=relu(d*acc+b1); q = d * (h@W2). Wave/row.
__global__ __launch_bounds__(256) void k3r(const float* __restrict__ part, const double* __restrict__ d,
                                           const float* __restrict__ b1, const float* __restrict__ W2,
                                           float* __restrict__ q, int kspl) {
    int row = blockIdx.x * 4 + (threadIdx.x >> 6);
    int f = threadIdx.x & 63;
    double acc = 0.0;
    for (int ks = 0; ks < kspl; ++ks)
        acc += (double)part[((size_t)ks * NN + row) * 64 + f];
    double di = d[row];
    double h = di * acc + (double)b1[f];
    h = h > 0.0 ? h : 0.0;
    double t0 = h * (double)W2[f * 2 + 0];
    double t1 = h * (double)W2[f * 2 + 1];
#pragma unroll
    for (int o = 32; o > 0; o >>= 1) {
        t0 += __shfl_down(t0, o);
        t1 += __shfl_down(t1, o);
    }
    if (f == 0) {
        q[(size_t)row * 2 + 0] = (float)(di * t0);
        q[(size_t)row * 2 + 1] = (float)(di * t1);
    }
}

// ---------------- K4: agg2, fp64, wave/row. (proven in r3) ----------------
__global__ __launch_bounds__(256) void k4(const float* __restrict__ adj, const float* __restrict__ q,
                                          const double* __restrict__ d, const float* __restrict__ b2,
                                          float* __restrict__ out) {
    int row = blockIdx.x * 4 + (threadIdx.x >> 6);
    int l = threadIdx.x & 63;
    const float4* a = (const float4*)(adj + (size_t)row * NN) + l;
    const float4* qv = (const float4*)q;
    double acc0 = 0.0, acc1 = 0.0;
#pragma unroll 4
    for (int it = 0; it < 32; ++it) {
        float4 av = a[(size_t)it * 64];
        size_t jv = ((size_t)it * 64 + l) * 2;
        float4 qa = qv[jv];
        float4 qb = qv[jv + 1];
        acc0 += (double)av.x * qa.x + (double)av.y * qa.z + (double)av.z * qb.x + (double)av.w * qb.z;
        acc1 += (double)av.x * qa.y + (double)av.y * qa.w + (double)av.z * qb.y + (double)av.w * qb.w;
    }
#pragma unroll
    for (int o = 32; o > 0; o >>= 1) {
        acc0 += __shfl_down(acc0, o);
        acc1 += __shfl_down(acc1, o);
    }
    if (l == 0) {
        double di = d[row];
        out[(size_t)row * 2 + 0] = (float)(di * acc0 + (double)b2[0]);
        out[(size_t)row * 2 + 1] = (float)(di * acc1 + (double)b2[1]);
    }
}

// ---------------- Path B fallback (round-3 proven fp64 kernels) ----------------
__global__ __launch_bounds__(256) void k2f(const float* __restrict__ x, const float* __restrict__ W1,
                                           const double* __restrict__ d, float* __restrict__ P) {
    __shared__ float sw[128 * 64];
    __shared__ float sx[16 * 128];
    int tid = threadIdx.x;
    int jb = blockIdx.x * 16;
#pragma unroll
    for (int o = 0; o < 8; ++o)
        ((float4*)sw)[tid * 8 + o] = ((const float4*)W1)[tid * 8 + o];
#pragma unroll
    for (int o = 0; o < 2; ++o)
        ((float4*)sx)[tid * 2 + o] = ((const float4*)(x + (size_t)jb * 128))[tid * 2 + o];
    __syncthreads();
    int f = tid & 63, g = tid >> 6;
    double acc[4] = {};
    for (int c = 0; c < 128; ++c) {
        double w = (double)sw[c * 64 + f];
#pragma unroll
        for (int rr = 0; rr < 4; ++rr)
            acc[rr] += (double)sx[(g * 4 + rr) * 128 + c] * w;
    }
#pragma unroll
    for (int rr = 0; rr < 4; ++rr) {
        int j = jb + g * 4 + rr;
        P[(size_t)j * 64 + f] = (float)(acc[rr] * d[j]);
    }
}
__global__ __launch_bounds__(256) void k3f(const float* __restrict__ adj, const float* __restrict__ P,
                                           const double* __restrict__ d, const float* __restrict__ b1,
                                           const float* __restrict__ W2, float* __restrict__ q) {
    __shared__ float sp[128 * 64];
    __shared__ float sa[16 * 128];
    int tid = threadIdx.x;
    int f = tid & 63, g = tid >> 6;
    int rb = blockIdx.x * 16;
    double acc[4] = {};
    for (int ch = 0; ch < 64; ++ch) {
        __syncthreads();
#pragma unroll
        for (int o = 0; o < 8; ++o)
            ((float4*)sp)[tid * 8 + o] = ((const float4*)(P + (size_t)ch * 128 * 64))[tid * 8 + o];
#pragma unroll
        for (int o = 0; o < 2; ++o) {
            int t = tid * 2 + o;
            int r = t >> 5, cv = t & 31;
            ((float4*)(sa + r * 128))[cv] = *(const float4*)(adj + (size_t)(rb + r) * NN + ch * 128 + cv * 4);
        }
        __syncthreads();
        const float* sar = sa + g * 4 * 128;
        for (int jj = 0; jj < 128; jj += 4) {
            float4 a0 = *(const float4*)(sar + jj);
            float4 a1 = *(const float4*)(sar + 128 + jj);
            float4 a2 = *(const float4*)(sar + 256 + jj);
            float4 a3 = *(const float4*)(sar + 384 + jj);
            double p0 = (double)sp[(jj + 0) * 64 + f];
            double p1 = (double)sp[(jj + 1) * 64 + f];
            double p2 = (double)sp[(jj + 2) * 64 + f];
            double p3 = (double)sp[(jj + 3) * 64 + f];
            acc[0] += (double)a0.x * p0 + (double)a0.y * p1 + (double)a0.z * p2 + (double)a0.w * p3;
            acc[1] += (double)a1.x * p0 + (double)a1.y * p1 + (double)a1.z * p2 + (double)a1.w * p3;
            acc[2] += (double)a2.x * p0 + (double)a2.y * p1 + (double)a2.z * p2 + (double)a2.w * p3;
            acc[3] += (double)a3.x * p0 + (double)a3.y * p1 + (double)a3.z * p2 + (double)a3.w * p3;
        }
    }
    double w0 = (double)W2[f * 2 + 0], w1 = (double)W2[f * 2 + 1], bb = (double)b1[f];
#pragma unroll
    for (int rr = 0; rr < 4; ++rr) {
        int row = rb + g * 4 + rr;
        double di = d[row];
        double h = di * acc[rr] + bb;
        h = h > 0.0 ? h : 0.0;
        double t0 = h * w0, t1 = h * w1;
#pragma unroll
        for (int o = 32; o > 0; o >>= 1) {
            t0 += __shfl_down(t0, o);
            t1 += __shfl_down(t1, o);
        }
        if (f == 0) {
            q[(size_t)row * 2 + 0] = (float)(di * t0);
            q[(size_t)row * 2 + 1] = (float)(di * t1);
        }
    }
}

extern "C" void kernel_launch(void* const* d_in, const int* in_sizes, int n_in,
                              void* d_out, int out_size, void* d_ws, size_t ws_size,
                              hipStream_t stream) {
    const float* x   = (const float*)d_in[0];
    const float* adj = (const float*)d_in[1];
    const float* W1  = (const float*)d_in[2];
    const float* b1  = (const float*)d_in[3];
    const float* W2  = (const float*)d_in[4];
    const float* b2  = (const float*)d_in[5];
    float* out = (float*)d_out;

    char* ws = (char*)d_ws;
    double* dvec = (double*)ws;  // 64 KB

    int kspl = 0;
    for (int c : {8, 4, 2, 1}) {
        size_t need = 65536 + 3u * 1048576u + (size_t)c * 2097152u + 65536u;
        if (ws_size >= need) { kspl = c; break; }
    }

    k1<<<2048, 256, 0, stream>>>(adj, dvec);
    if (kspl > 0) {
        u16* Ph = (u16*)(ws + 65536);
        u16* Pm = Ph + (size_t)64 * NN;
        u16* Pl = Pm + (size_t)64 * NN;
        float* part = (float*)(ws + 65536 + 3u * 1048576u);
        float* q = (float*)(ws + 65536 + 3u * 1048576u + (size_t)kspl * 2097152u);
        k2s<<<256, 256, 0, stream>>>(x, W1, dvec, Ph, Pm, Pl);
        k3s<<<64 * kspl, 256, 0, stream>>>(adj, Ph, Pm, Pl, part, kspl, NN / kspl);
        k3r<<<2048, 256, 0, stream>>>(part, dvec, b1, W2, q, kspl);
        k4<<<2048, 256, 0, stream>>>(adj, q, dvec, b2, out);
    } else {
        float* P = (float*)(ws + 65536);
        float* q = (float*)(ws + 65536 + 2097152);
        k2f<<<512, 256, 0, stream>>>(x, W1, dvec, P);
        k3f<<<512, 256, 0, stream>>>(adj, P, dvec, b1, W2, q);
        k4<<<2048, 256, 0, stream>>>(adj, q, dvec, b2, out);
    }
}